// Round 1
// baseline (1404.760 us; speedup 1.0000x reference)
//
#include <hip/hip_runtime.h>

// EquivariantSubsample: shifted 2x2 max-pool.
//   images: [B=16, C=64, H=512, W=512] fp32
//   p_w, p_h: [B, C] int32 in {0,1}
//   out: [B, C, 256, 256] fp32
//   out[b,c,oy,ox] = max over 2x2 block at (min(ph+2*oy, H-2), min(pw+2*ox, W-2))

#define H 512
#define W 512
#define OH 256
#define OW 256

__global__ __launch_bounds__(256) void equivariant_subsample_kernel(
    const float* __restrict__ img,
    const int* __restrict__ p_w,
    const int* __restrict__ p_h,
    float* __restrict__ out)
{
    const int t  = threadIdx.x;                       // lane within wave, 0..63
    const int bc = blockIdx.x >> 6;                   // (b*C + c), uniform per block
    const int oy = ((blockIdx.x & 63) << 2) + threadIdx.y;  // output row 0..255

    // Block-uniform -> scalar loads
    const int ph = p_h[bc];
    const int pw = p_w[bc];

    // Row clamp: y0 = min(ph + 2*oy, H-2); y1 = y0+1 (always <= 511)
    int y0 = ph + 2 * oy;
    if (y0 > H - 2) y0 = H - 2;

    const float* row0 = img + ((size_t)bc * H + (size_t)y0) * W;
    const float* row1 = row0 + W;

    // Lane t covers input columns [8t, 8t+7] of both rows: two aligned float4 each.
    const float4 a0 = *(const float4*)(row0 + 8 * t);
    const float4 b0 = *(const float4*)(row0 + 8 * t + 4);
    const float4 a1 = *(const float4*)(row1 + 8 * t);
    const float4 b1 = *(const float4*)(row1 + 8 * t + 4);

    float4 r;
    if (pw == 0) {
        // Pairs: (8t,8t+1) (8t+2,8t+3) (8t+4,8t+5) (8t+6,8t+7)
        r.x = fmaxf(fmaxf(a0.x, a0.y), fmaxf(a1.x, a1.y));
        r.y = fmaxf(fmaxf(a0.z, a0.w), fmaxf(a1.z, a1.w));
        r.z = fmaxf(fmaxf(b0.x, b0.y), fmaxf(b1.x, b1.y));
        r.w = fmaxf(fmaxf(b0.z, b0.w), fmaxf(b1.z, b1.w));
    } else {
        // pw == 1. Pairs: (8t+1,8t+2) (8t+3,8t+4) (8t+5,8t+6) (8t+7,8t+8)
        // The last pair needs element 8t+8 = next lane's a.x -> shuffle, no extra load.
        const float e0 = __shfl_down(a0.x, 1);
        const float e1 = __shfl_down(a1.x, 1);
        r.x = fmaxf(fmaxf(a0.y, a0.z), fmaxf(a1.y, a1.z));
        r.y = fmaxf(fmaxf(a0.w, b0.x), fmaxf(a1.w, b1.x));
        r.z = fmaxf(fmaxf(b0.y, b0.z), fmaxf(b1.y, b1.z));
        if (t == 63) {
            // Global last pixel: x_start clamped to 510 -> pair (510,511) = (b.z, b.w)
            r.w = fmaxf(fmaxf(b0.z, b0.w), fmaxf(b1.z, b1.w));
        } else {
            r.w = fmaxf(fmaxf(b0.w, e0), fmaxf(b1.w, e1));
        }
    }

    // Aligned float4 store of 4 consecutive output pixels.
    float4* o = (float4*)(out + ((size_t)bc * OH + (size_t)oy) * OW + 4 * t);
    *o = r;
}

extern "C" void kernel_launch(void* const* d_in, const int* in_sizes, int n_in,
                              void* d_out, int out_size, void* d_ws, size_t ws_size,
                              hipStream_t stream) {
    const float* img = (const float*)d_in[0];
    const int* pw = (const int*)d_in[1];
    const int* ph = (const int*)d_in[2];
    float* out = (float*)d_out;

    // 16*64 (b,c) slices * 64 blocks each (4 output rows per block)
    dim3 grid(16 * 64 * 64);
    dim3 block(64, 4);
    equivariant_subsample_kernel<<<grid, block, 0, stream>>>(img, pw, ph, out);
}